// Round 4
// baseline (1146.267 us; speedup 1.0000x reference)
//
#include <hip/hip_runtime.h>
#include <hip/hip_bf16.h>

// Problem: out[i0,i2,i1] = sum_r f0[i0,r]*f2[i2,r]*f1[i1,r]
// N0=512, N1=512, N2=256, R=32.
// Inputs fp32 (R1: bf16 reinterpret -> NaN). Output fp32 (harness contract:
// reference returns float32 -> d_out is float*; R2/R3 identical absmax 62.875
// from two independent kernels pinned the bug to the bf16 output writes).
//
// GEMM view: C[p,i1] = sum_r G[p,r]*f1[i1,r], G = f0 (x) f2 Khatri-Rao, K=32.
// Roofline: 268 MB fp32 out -> ~43 us at 6.3 TB/s (write-bound).
// VALU compute: 2.15 G FMA ~27 us at 157 TF -> hides under writes; no MFMA needed.

#define N0 512
#define N1 512
#define N2 256
#define R  32

typedef float floatx4 __attribute__((ext_vector_type(4)));

__global__ __launch_bounds__(256, 4)
void cp_valu_kernel(const float* __restrict__ f0,
                    const float* __restrict__ f1,
                    const float* __restrict__ f2,
                    float* __restrict__ out) {
    const int tid = threadIdx.x;
    const int m   = tid >> 4;        // p-row within block: 0..15
    const int g   = tid & 15;        // i1 sub-position: 0..15

    const int  blk = blockIdx.x;
    const int  i0  = blk >> 4;
    const int  i2  = ((blk & 15) << 4) + m;
    const long p   = (long)blk * 16 + m;   // p = i0*256 + i2

    // G[r] = f0[i0][r] * f2[i2][r]  (fp32, exact)
    float G[R];
    {
        const floatx4* a = (const floatx4*)(f0 + i0 * R);
        const floatx4* b = (const floatx4*)(f2 + i2 * R);
        #pragma unroll
        for (int v = 0; v < 8; ++v) {
            const floatx4 x = a[v];
            const floatx4 y = b[v];
            G[4 * v + 0] = x[0] * y[0];
            G[4 * v + 1] = x[1] * y[1];
            G[4 * v + 2] = x[2] * y[2];
            G[4 * v + 3] = x[3] * y[3];
        }
    }

    float* orow = out + p * (long)N1;

    // Thread covers i1 in 4 chunks of 8: [c*128 + g*8, +8).
    // 16 threads of a g-group write 16x32 B = 512 B contiguous per chunk.
    #pragma unroll
    for (int c = 0; c < 4; ++c) {
        const int col0 = c * 128 + g * 8;
        floatx4 lo, hi;
        #pragma unroll
        for (int j = 0; j < 8; ++j) {
            const floatx4* frow = (const floatx4*)(f1 + (col0 + j) * R);
            float acc = 0.f;
            #pragma unroll
            for (int v = 0; v < 8; ++v) {
                const floatx4 x = frow[v];
                acc += G[4 * v + 0] * x[0];
                acc += G[4 * v + 1] * x[1];
                acc += G[4 * v + 2] * x[2];
                acc += G[4 * v + 3] * x[3];
            }
            if (j < 4) lo[j] = acc; else hi[j - 4] = acc;
        }
        *(floatx4*)(orow + col0)     = lo;
        *(floatx4*)(orow + col0 + 4) = hi;
    }
}

extern "C" void kernel_launch(void* const* d_in, const int* in_sizes, int n_in,
                              void* d_out, int out_size, void* d_ws, size_t ws_size,
                              hipStream_t stream) {
    const float* f0 = (const float*)d_in[0];
    const float* f1 = (const float*)d_in[1];
    const float* f2 = (const float*)d_in[2];
    float* out = (float*)d_out;

    const int n_blocks = (N0 * N2) / 16;  // 8192 blocks x 256 threads
    cp_valu_kernel<<<dim3(n_blocks), dim3(256), 0, stream>>>(f0, f1, f2, out);
}

// Round 5
// 293.649 us; speedup vs baseline: 3.9035x; 3.9035x over previous
//
#include <hip/hip_runtime.h>
#include <hip/hip_bf16.h>

// out[i0,i2,i1] = sum_r f0[i0,r]*f2[i2,r]*f1[i1,r]; N0=512,N1=512,N2=256,R=32.
// Inputs fp32, output fp32 (proven R4). GEMM: C[p,i1] = G[p,:].f1[i1,:]^T,
// G = KR(f0,f2), M=131072, N=512, K=32 -> one mfma_f32_16x16x32_bf16 per tile.
// R4 post-mortem: VALU version latency-bound (958 us, VALUBusy 7.9%, 257 cyc/load).
// MFMA version: 14x fewer VMEM ops/lane, reduction in matrix pipe, streaming stores.
// R2==R3 bit-identical absmax proves these fragment layouts are correct.
// Floor: 268 MB fp32 out / 6.3 TB/s = 43 us.

#define N0 512
#define N1 512
#define N2 256
#define R  32

typedef __bf16  bf16x8  __attribute__((ext_vector_type(8)));
typedef float   floatx4 __attribute__((ext_vector_type(4)));

#define LDS_STRIDE 516  // floats; rows shift 4 banks -> D-stage writes are 2-way (free)

__global__ __launch_bounds__(256, 4)
void cp_mfma_kernel(const float* __restrict__ f0,
                    const float* __restrict__ f1,
                    const float* __restrict__ f2,
                    float* __restrict__ out) {
    __shared__ float lds[16 * LDS_STRIDE];  // 33 KB -> 4 blocks/CU

    const int tid  = threadIdx.x;
    const int wave = tid >> 6;
    const int lane = tid & 63;
    const int n    = lane & 15;   // A: m index; B: n index; D: col index
    const int q    = lane >> 4;   // quad

    const int blk     = blockIdx.x;
    const int i0      = blk >> 4;
    const int i2_base = (blk & 15) << 4;
    const long p_base = (long)blk * 16;

    // ---- A fragment: A[m=n][k=q*8+j] = bf16( f0[i0][k] * f2[i2_base+n][k] )
    bf16x8 a;
    {
        const floatx4 v0a = *(const floatx4*)(f0 + i0 * R + q * 8);
        const floatx4 v0b = *(const floatx4*)(f0 + i0 * R + q * 8 + 4);
        const floatx4 v2a = *(const floatx4*)(f2 + (i2_base + n) * R + q * 8);
        const floatx4 v2b = *(const floatx4*)(f2 + (i2_base + n) * R + q * 8 + 4);
        #pragma unroll
        for (int j = 0; j < 4; ++j) {
            a[j]     = (__bf16)(v0a[j] * v2a[j]);
            a[j + 4] = (__bf16)(v0b[j] * v2b[j]);
        }
    }

    // ---- 8 MFMAs: wave covers i1 cols [wave*128, +128)
    const int colbase = wave * 128;
    floatx4 acc[8];
    #pragma unroll
    for (int t = 0; t < 8; ++t) {
        const float* f1p = f1 + (colbase + t * 16 + n) * R + q * 8;
        const floatx4 ba = *(const floatx4*)(f1p);
        const floatx4 bb = *(const floatx4*)(f1p + 4);
        bf16x8 b;
        #pragma unroll
        for (int j = 0; j < 4; ++j) {
            b[j]     = (__bf16)ba[j];
            b[j + 4] = (__bf16)bb[j];
        }
        floatx4 c = {0.f, 0.f, 0.f, 0.f};
        acc[t] = __builtin_amdgcn_mfma_f32_16x16x32_bf16(a, b, c, 0, 0, 0);
    }

    // ---- stage D to LDS fp32, row-major [p-row][i1-col]
    // D layout: col = lane&15, row = q*4 + v  (verified: R2==R3 outputs + m89)
    #pragma unroll
    for (int t = 0; t < 8; ++t) {
        const int col = colbase + t * 16 + n;
        #pragma unroll
        for (int v = 0; v < 4; ++v) {
            lds[(q * 4 + v) * LDS_STRIDE + col] = acc[t][v];
        }
    }
    __syncthreads();

    // ---- coalesced out: block's 16x512 fp32 = 32 KB contiguous region
    float* outp = out + p_base * (long)N1;
    #pragma unroll
    for (int k = 0; k < 8; ++k) {
        const int idx = (tid + k * 256) * 4;  // 0 .. 8191 floats
        const int row = idx >> 9;
        const int col = idx & 511;
        *(floatx4*)(outp + idx) = *(const floatx4*)&lds[row * LDS_STRIDE + col];
    }
}

extern "C" void kernel_launch(void* const* d_in, const int* in_sizes, int n_in,
                              void* d_out, int out_size, void* d_ws, size_t ws_size,
                              hipStream_t stream) {
    const float* f0 = (const float*)d_in[0];
    const float* f1 = (const float*)d_in[1];
    const float* f2 = (const float*)d_in[2];
    float* out = (float*)d_out;

    const int n_blocks = (N0 * N2) / 16;  // 8192
    cp_mfma_kernel<<<dim3(n_blocks), dim3(256), 0, stream>>>(f0, f1, f2, out);
}